// Round 10
// baseline (31.625 us; speedup 1.0000x reference)
//
#include <hip/hip_runtime.h>

#define M_COLS 2048
#define KOUT 64
#define CAND 128
#define BLK 256  // 4 waves/block, 1 row/wave

typedef unsigned long long u64;

// ---- DPP move (pure VALU): quad_perm / row_shr / row_bcast
#define DPPU(old, src, ctrl, rmask) \
  ((unsigned)__builtin_amdgcn_update_dpp((int)(old), (int)(src), (ctrl), (rmask), 0xF, false))
#define RDL(x, l) ((unsigned)__builtin_amdgcn_readlane((int)(x), (l)))

#define SCAN_MAX_U(x)                                  \
  do {                                                 \
    unsigned _t;                                       \
    _t = DPPU(0u, x, 0x111, 0xF); x = x > _t ? x : _t; \
    _t = DPPU(0u, x, 0x112, 0xF); x = x > _t ? x : _t; \
    _t = DPPU(0u, x, 0x114, 0xF); x = x > _t ? x : _t; \
    _t = DPPU(0u, x, 0x118, 0xF); x = x > _t ? x : _t; \
    _t = DPPU(0u, x, 0x142, 0xA); x = x > _t ? x : _t; \
    _t = DPPU(0u, x, 0x143, 0xC); x = x > _t ? x : _t; \
  } while (0)

#define SCAN_ADD_F(x)                                               \
  do {                                                              \
    x += __uint_as_float(DPPU(0u, __float_as_uint(x), 0x111, 0xF)); \
    x += __uint_as_float(DPPU(0u, __float_as_uint(x), 0x112, 0xF)); \
    x += __uint_as_float(DPPU(0u, __float_as_uint(x), 0x114, 0xF)); \
    x += __uint_as_float(DPPU(0u, __float_as_uint(x), 0x118, 0xF)); \
    x += __uint_as_float(DPPU(0u, __float_as_uint(x), 0x142, 0xA)); \
    x += __uint_as_float(DPPU(0u, __float_as_uint(x), 0x143, 0xC)); \
  } while (0)

// lanes-below-me popcount of a 64-bit mask
#define MB64(m)                                         \
  __builtin_amdgcn_mbcnt_hi((unsigned)((m) >> 32),      \
      __builtin_amdgcn_mbcnt_lo((unsigned)(m), 0u))

// xor-lane exchange within 32-lane halves via ds_swizzle (BitMode: (xor<<10)|0x1f)
#define SWZ(v, J) ((unsigned)__builtin_amdgcn_ds_swizzle((int)(v), (((J) << 10) | 0x1f)))

#define EX_S(dst, src, J)                           \
  do {                                              \
    unsigned _lo = SWZ((unsigned)(src), J);         \
    unsigned _hi = SWZ((unsigned)((src) >> 32), J); \
    dst = ((u64)_hi << 32) | _lo;                   \
  } while (0)
#define EX_D(dst, src, CTRL)                                     \
  do {                                                           \
    unsigned _lo = DPPU(0u, (unsigned)(src), CTRL, 0xF);         \
    unsigned _hi = DPPU(0u, (unsigned)((src) >> 32), CTRL, 0xF); \
    dst = ((u64)_hi << 32) | _lo;                                \
  } while (0)
#define EX_W(dst, src)                                                         \
  do {                                                                         \
    unsigned _lo = (unsigned)__shfl_xor((int)(unsigned)(src), 32, 64);         \
    unsigned _hi = (unsigned)__shfl_xor((int)(unsigned)((src) >> 32), 32, 64); \
    dst = ((u64)_hi << 32) | _lo;                                              \
  } while (0)

#define CMPSEL(up)                       \
  do {                                   \
    k0 = ((k0 >= o0) == (up)) ? k0 : o0; \
    k1 = ((k1 >= o1) == (up)) ? o1 : k1; \
  } while (0)

#define STEP_A_S(J, UP) do { u64 o0, o1; EX_S(o0, k0, J); EX_S(o1, k1, J); CMPSEL(UP); } while (0)
#define STEP_A_D(CTRL, UP) do { u64 o0, o1; EX_D(o0, k0, CTRL); EX_D(o1, k1, CTRL); CMPSEL(UP); } while (0)
#define STEP_A_W(UP) do { u64 o0, o1; EX_W(o0, k0); EX_W(o1, k1); CMPSEL(UP); } while (0)

#define STEP_B_S(J, UP) do { u64 o; EX_S(o, av, J); av = ((av >= o) == (UP)) ? av : o; } while (0)
#define STEP_B_D(CTRL, UP) do { u64 o; EX_D(o, av, CTRL); av = ((av >= o) == (UP)) ? av : o; } while (0)
#define STEP_B_W(UP) do { u64 o; EX_W(o, av); av = ((av >= o) == (UP)) ? av : o; } while (0)

__global__ __launch_bounds__(BLK) void topk_route_kernel(
    const float* __restrict__ A, const int* __restrict__ topk,
    float* __restrict__ out_w, float* __restrict__ out_i, int NQ, int Q, int N) {
  __shared__ u64 cand[4][CAND];

  const unsigned tid = threadIdx.x;
  const unsigned wv = tid >> 6, lane = tid & 63u;
  const unsigned row = blockIdx.x * 4u + wv;
  if ((int)row >= NQ) return;
  const unsigned n = row / (unsigned)Q;

  const float4* a4 = (const float4*)(A + (size_t)row * M_COLS);
  u64* cw = &cand[wv][0];
  const unsigned lob = 2047u - 4u * lane;  // key low base; low = lob - (256t + c)

  // ---- branch-free topk sniff (int64 vs int32 layout; uniform)
  int kk;
  if (N >= 8) {
    const int4* t4 = (const int4*)topk;
    int4 a = t4[0], b = t4[1], c = t4[2], d = t4[3];
    int k64 = topk[2 * (int)n], k32 = topk[(int)n];
    bool looks64 = (a.y == 0) & (a.w == 0) & (b.y == 0) & (b.w == 0) &
                   (c.y == 0) & (c.w == 0) & (d.y == 0) & (d.w == 0) &
                   (a.x >= 1) & (a.z >= 1) & (b.x >= 1) & (b.z >= 1) &
                   (c.x >= 1) & (c.z >= 1) & (d.x >= 1) & (d.z >= 1);
    kk = looks64 ? k64 : k32;
  } else {
    bool looks64 = true;
    for (int i = 0; i < N; ++i) {
      int l = topk[2 * i], h = topk[2 * i + 1];
      if (h != 0 || l < 1) { looks64 = false; break; }
    }
    kk = looks64 ? topk[2 * (int)n] : topk[(int)n];
  }
  kk = kk > M_COLS ? M_COLS : (kk < 0 ? 0 : kk);

  // index-ordered streaming compaction of one arriving float4 (batch t, thresh T)
  unsigned base = 0u;  // wave-uniform running survivor count (scalar pipe)
  auto compact4 = [&](float4 vv, int t, unsigned T) {
    unsigned b0 = __float_as_uint(vv.x) & 0x7fffffffu;
    unsigned b1 = __float_as_uint(vv.y) & 0x7fffffffu;
    unsigned b2 = __float_as_uint(vv.z) & 0x7fffffffu;
    unsigned b3 = __float_as_uint(vv.w) & 0x7fffffffu;
    bool p0 = b0 >= T, p1 = b1 >= T, p2 = b2 >= T, p3 = b3 >= T;
    u64 m0 = __ballot(p0), m1 = __ballot(p1), m2 = __ballot(p2), m3 = __ballot(p3);
    unsigned mba = MB64(m0) + MB64(m1) + MB64(m2) + MB64(m3);  // lanes below me
    unsigned l1 = (unsigned)p0, l2 = l1 + (unsigned)p1, l3 = l2 + (unsigned)p2;
    unsigned pb = base + mba;
    if (p0 && pb < CAND)      cw[pb]      = ((u64)b0 << 32) | (u64)(lob - (unsigned)(256 * t + 0));
    if (p1 && pb + l1 < CAND) cw[pb + l1] = ((u64)b1 << 32) | (u64)(lob - (unsigned)(256 * t + 1));
    if (p2 && pb + l2 < CAND) cw[pb + l2] = ((u64)b2 << 32) | (u64)(lob - (unsigned)(256 * t + 2));
    if (p3 && pb + l3 < CAND) cw[pb + l3] = ((u64)b3 << 32) | (u64)(lob - (unsigned)(256 * t + 3));
    base += (unsigned)__popcll(m0) + (unsigned)__popcll(m1) +
            (unsigned)__popcll(m2) + (unsigned)__popcll(m3);
  };

  // ---- FAST PATH: fixed probe |x| >= 2.0 (N(0,1): count ~93, in [64,128] w.p. ~.999)
  // Issue all 8 loads; compact each as it arrives (latency hidden by construction).
  {
    float4 v0 = a4[lane];          float4 v1 = a4[lane + 64u];
    float4 v2 = a4[lane + 128u];   float4 v3 = a4[lane + 192u];
    float4 v4 = a4[lane + 256u];   float4 v5 = a4[lane + 320u];
    float4 v6 = a4[lane + 384u];   float4 v7 = a4[lane + 448u];
    compact4(v0, 0, 0x40000000u);  compact4(v1, 1, 0x40000000u);
    compact4(v2, 2, 0x40000000u);  compact4(v3, 3, 0x40000000u);
    compact4(v4, 4, 0x40000000u);  compact4(v5, 5, 0x40000000u);
    compact4(v6, 6, 0x40000000u);  compact4(v7, 7, 0x40000000u);
  }

  if (base < KOUT || base > CAND) {
    // ---- SLOW PATH (exact, any data): reload-based cascade; rows are L1/L2-hot.
    auto count_ge = [&](unsigned T) -> unsigned {
      unsigned c = 0u;
      for (int t = 0; t < 8; ++t) {
        float4 vv = a4[lane + 64u * (unsigned)t];
        c += (unsigned)__popcll(__ballot((__float_as_uint(vv.x) & 0x7fffffffu) >= T));
        c += (unsigned)__popcll(__ballot((__float_as_uint(vv.y) & 0x7fffffffu) >= T));
        c += (unsigned)__popcll(__ballot((__float_as_uint(vv.z) & 0x7fffffffu) >= T));
        c += (unsigned)__popcll(__ballot((__float_as_uint(vv.w) & 0x7fffffffu) >= T));
      }
      return c;  // wave-uniform
    };

    // wave max -> em
    unsigned mx = 0u;
    for (int t = 0; t < 8; ++t) {
      float4 vv = a4[lane + 64u * (unsigned)t];
      unsigned c0 = __float_as_uint(vv.x) & 0x7fffffffu;
      unsigned c1 = __float_as_uint(vv.y) & 0x7fffffffu;
      unsigned c2 = __float_as_uint(vv.z) & 0x7fffffffu;
      unsigned c3 = __float_as_uint(vv.w) & 0x7fffffffu;
      unsigned m01 = c0 > c1 ? c0 : c1, m23 = c2 > c3 ? c2 : c3;
      unsigned mm = m01 > m23 ? m01 : m23;
      mx = mm > mx ? mm : mx;
    }
    SCAN_MAX_U(mx);
    mx = RDL(mx, 63);
    const int em = (int)(mx >> 23);

    // probe em, em-1, em-2, 0
    unsigned lo, hi = mx + 1u, csel;
    {
      unsigned T = (em > 0) ? ((unsigned)em << 23) : 0u;
      csel = count_ge(T); lo = T;
      if (csel < KOUT) {
        hi = T;
        T = (em - 1 > 0) ? ((unsigned)(em - 1) << 23) : 0u;
        csel = count_ge(T); lo = T;
        if (csel < KOUT) {
          hi = T;
          T = (em - 2 > 0) ? ((unsigned)(em - 2) << 23) : 0u;
          csel = count_ge(T); lo = T;
          if (csel < KOUT) { hi = T; lo = 0u; csel = count_ge(0u); }
        }
      }
    }
    // binary refine until 64 <= count(>=lo) <= 128 (or ties: lo+1 == hi)
    while (csel > CAND && lo + 1u < hi) {
      unsigned mid = lo + ((hi - lo) >> 1);
      unsigned c = count_ge(mid);
      if (c >= KOUT) { lo = mid; csel = c; } else hi = mid;
    }

    base = 0u;
    if (csel <= CAND) {
      for (int t = 0; t < 8; ++t) compact4(a4[lane + 64u * (unsigned)t], t, lo);
    } else {
      // >128 bit-exact ties at lo: keep all > lo (i.e. >= hi), then smallest-index
      // ties (== lo) up to capacity; compact4's index-ordered positions + <CAND
      // guard implement the index-order trim exactly.
      for (int t = 0; t < 8; ++t) compact4(a4[lane + 64u * (unsigned)t], t, hi);
      for (int t = 0; t < 8; ++t) {
        float4 vv = a4[lane + 64u * (unsigned)t];
        unsigned b0 = __float_as_uint(vv.x) & 0x7fffffffu;
        unsigned b1 = __float_as_uint(vv.y) & 0x7fffffffu;
        unsigned b2 = __float_as_uint(vv.z) & 0x7fffffffu;
        unsigned b3 = __float_as_uint(vv.w) & 0x7fffffffu;
        bool p0 = b0 == lo, p1 = b1 == lo, p2 = b2 == lo, p3 = b3 == lo;
        u64 m0 = __ballot(p0), m1 = __ballot(p1), m2 = __ballot(p2), m3 = __ballot(p3);
        unsigned mba = MB64(m0) + MB64(m1) + MB64(m2) + MB64(m3);
        unsigned l1 = (unsigned)p0, l2 = l1 + (unsigned)p1, l3 = l2 + (unsigned)p2;
        unsigned pb = base + mba;
        if (p0 && pb < CAND)      cw[pb]      = ((u64)b0 << 32) | (u64)(lob - (unsigned)(256 * t + 0));
        if (p1 && pb + l1 < CAND) cw[pb + l1] = ((u64)b1 << 32) | (u64)(lob - (unsigned)(256 * t + 1));
        if (p2 && pb + l2 < CAND) cw[pb + l2] = ((u64)b2 << 32) | (u64)(lob - (unsigned)(256 * t + 2));
        if (p3 && pb + l3 < CAND) cw[pb + l3] = ((u64)b3 << 32) | (u64)(lob - (unsigned)(256 * t + 3));
        base += (unsigned)__popcll(m0) + (unsigned)__popcll(m1) +
                (unsigned)__popcll(m2) + (unsigned)__popcll(m3);
      }
      base = base > CAND ? CAND : base;
    }
  }

  // ---- pad empty slots [base, 128) with 0-keys (base >= 64 guaranteed)
  {
    unsigned pz0 = base + lane, pz1 = base + 64u + lane;
    if (pz0 < CAND) cw[pz0] = 0ull;
    if (pz1 < CAND) cw[pz1] = 0ull;
  }

  // ---- per-stage comparator flags from lane bits
  const bool b1 = (lane & 1u) != 0u, b2 = (lane & 2u) != 0u, b4 = (lane & 4u) != 0u;
  const bool b8 = (lane & 8u) != 0u, b16 = (lane & 16u) != 0u, b32 = (lane & 32u) != 0u;

  // ---- sort: k0 desc + k1 asc (21 dual stages), local exchange, merge top half
  u64 k0 = cw[lane];
  u64 k1 = cw[lane + 64u];
  // k=2
  STEP_A_D(0xB1, !(b2 ^ b1));
  // k=4
  STEP_A_D(0x4E, !(b4 ^ b2)); STEP_A_D(0xB1, !(b4 ^ b1));
  // k=8
  STEP_A_S(4, !(b8 ^ b4)); STEP_A_D(0x4E, !(b8 ^ b2)); STEP_A_D(0xB1, !(b8 ^ b1));
  // k=16
  STEP_A_S(8, !(b16 ^ b8)); STEP_A_S(4, !(b16 ^ b4));
  STEP_A_D(0x4E, !(b16 ^ b2)); STEP_A_D(0xB1, !(b16 ^ b1));
  // k=32
  STEP_A_S(16, !(b32 ^ b16)); STEP_A_S(8, !(b32 ^ b8)); STEP_A_S(4, !(b32 ^ b4));
  STEP_A_D(0x4E, !(b32 ^ b2)); STEP_A_D(0xB1, !(b32 ^ b1));
  // k=64 (lane&64 == 0 always)
  STEP_A_W(!b32);
  STEP_A_S(16, !b16); STEP_A_S(8, !b8); STEP_A_S(4, !b4);
  STEP_A_D(0x4E, !b2); STEP_A_D(0xB1, !b1);

  u64 av = k0 >= k1 ? k0 : k1;  // bitonic; holds the top-64 set
  STEP_B_W(!b32);
  STEP_B_S(16, !b16); STEP_B_S(8, !b8); STEP_B_S(4, !b4);
  STEP_B_D(0x4E, !b2); STEP_B_D(0xB1, !b1);

  // ---- softmax over first kk entries; lane = rank (sorted desc)
  float val = __uint_as_float((unsigned)(av >> 32));
  unsigned midx = 2047u - (unsigned)(av & 0xffffffffull);
  bool valid = (int)lane < kk;

  float vmx = __uint_as_float(
      (unsigned)__builtin_amdgcn_readfirstlane((int)(unsigned)(av >> 32)));
  float e = valid ? __expf(val - vmx) : 0.0f;
  float s = e;
  SCAN_ADD_F(s);
  float stot = __uint_as_float(RDL(__float_as_uint(s), 63));
  float w = valid ? (e / stot) : 0.0f;

  size_t o = (size_t)row * KOUT + lane;
  out_w[o] = w;
  out_i[o] = valid ? (float)midx : 0.0f;
}

extern "C" void kernel_launch(void* const* d_in, const int* in_sizes, int n_in,
                              void* d_out, int out_size, void* d_ws, size_t ws_size,
                              hipStream_t stream) {
  const float* A = (const float*)d_in[0];
  const int* topk = (const int*)d_in[1];
  float* out = (float*)d_out;
  const int NQ = in_sizes[0] / M_COLS;
  const int N = in_sizes[1] > 0 ? in_sizes[1] : 1;
  const int Q = NQ / N;
  float* out_w = out;
  float* out_i = out + (size_t)NQ * KOUT;
  const int blocks = (NQ + 3) / 4;
  hipLaunchKernelGGL(topk_route_kernel, dim3(blocks), dim3(BLK), 0, stream, A,
                     topk, out_w, out_i, NQ, Q, N);
}

// Round 11
// 30.587 us; speedup vs baseline: 1.0340x; 1.0340x over previous
//
#include <hip/hip_runtime.h>

#define M_COLS 2048
#define KOUT 64
#define CAND 128
#define BLK 256  // 4 waves/block, 1 row/wave

typedef unsigned long long u64;

// ---- DPP move (pure VALU): quad_perm / row_shr / row_bcast
#define DPPU(old, src, ctrl, rmask) \
  ((unsigned)__builtin_amdgcn_update_dpp((int)(old), (int)(src), (ctrl), (rmask), 0xF, false))
#define RDL(x, l) ((unsigned)__builtin_amdgcn_readlane((int)(x), (l)))

// canonical wave64 inclusive scans: row_shr 1/2/4/8, bcast15 (rows 1,3), bcast31 (rows 2,3)
#define SCAN_ADD_U(x)             \
  do {                            \
    x += DPPU(0u, x, 0x111, 0xF); \
    x += DPPU(0u, x, 0x112, 0xF); \
    x += DPPU(0u, x, 0x114, 0xF); \
    x += DPPU(0u, x, 0x118, 0xF); \
    x += DPPU(0u, x, 0x142, 0xA); \
    x += DPPU(0u, x, 0x143, 0xC); \
  } while (0)

#define SCAN_MAX_U(x)                                  \
  do {                                                 \
    unsigned _t;                                       \
    _t = DPPU(0u, x, 0x111, 0xF); x = x > _t ? x : _t; \
    _t = DPPU(0u, x, 0x112, 0xF); x = x > _t ? x : _t; \
    _t = DPPU(0u, x, 0x114, 0xF); x = x > _t ? x : _t; \
    _t = DPPU(0u, x, 0x118, 0xF); x = x > _t ? x : _t; \
    _t = DPPU(0u, x, 0x142, 0xA); x = x > _t ? x : _t; \
    _t = DPPU(0u, x, 0x143, 0xC); x = x > _t ? x : _t; \
  } while (0)

#define SCAN_ADD_F(x)                                               \
  do {                                                              \
    x += __uint_as_float(DPPU(0u, __float_as_uint(x), 0x111, 0xF)); \
    x += __uint_as_float(DPPU(0u, __float_as_uint(x), 0x112, 0xF)); \
    x += __uint_as_float(DPPU(0u, __float_as_uint(x), 0x114, 0xF)); \
    x += __uint_as_float(DPPU(0u, __float_as_uint(x), 0x118, 0xF)); \
    x += __uint_as_float(DPPU(0u, __float_as_uint(x), 0x142, 0xA)); \
    x += __uint_as_float(DPPU(0u, __float_as_uint(x), 0x143, 0xC)); \
  } while (0)

// xor-lane exchange within 32-lane halves via ds_swizzle (BitMode: (xor<<10)|0x1f)
#define SWZ(v, J) ((unsigned)__builtin_amdgcn_ds_swizzle((int)(v), (((J) << 10) | 0x1f)))

// u64 partner fetch: ds_swizzle (J=4,8,16), quad_perm DPP (xor1=0xB1, xor2=0x4E), bpermute (32)
#define EX_S(dst, src, J)                           \
  do {                                              \
    unsigned _lo = SWZ((unsigned)(src), J);         \
    unsigned _hi = SWZ((unsigned)((src) >> 32), J); \
    dst = ((u64)_hi << 32) | _lo;                   \
  } while (0)
#define EX_D(dst, src, CTRL)                                     \
  do {                                                           \
    unsigned _lo = DPPU(0u, (unsigned)(src), CTRL, 0xF);         \
    unsigned _hi = DPPU(0u, (unsigned)((src) >> 32), CTRL, 0xF); \
    dst = ((u64)_hi << 32) | _lo;                                \
  } while (0)
#define EX_W(dst, src)                                                         \
  do {                                                                         \
    unsigned _lo = (unsigned)__shfl_xor((int)(unsigned)(src), 32, 64);         \
    unsigned _hi = (unsigned)__shfl_xor((int)(unsigned)((src) >> 32), 32, 64); \
    dst = ((u64)_hi << 32) | _lo;                                              \
  } while (0)

// dual compare-exchange: k0 descending, k1 ascending (mirrored)
#define CMPSEL(up)                       \
  do {                                   \
    k0 = ((k0 >= o0) == (up)) ? k0 : o0; \
    k1 = ((k1 >= o1) == (up)) ? o1 : k1; \
  } while (0)

#define STEP_A_S(J, UP) do { u64 o0, o1; EX_S(o0, k0, J); EX_S(o1, k1, J); CMPSEL(UP); } while (0)
#define STEP_A_D(CTRL, UP) do { u64 o0, o1; EX_D(o0, k0, CTRL); EX_D(o1, k1, CTRL); CMPSEL(UP); } while (0)
#define STEP_A_W(UP) do { u64 o0, o1; EX_W(o0, k0); EX_W(o1, k1); CMPSEL(UP); } while (0)

// descending bitonic merge stage on av
#define STEP_B_S(J, UP) do { u64 o; EX_S(o, av, J); av = ((av >= o) == (UP)) ? av : o; } while (0)
#define STEP_B_D(CTRL, UP) do { u64 o; EX_D(o, av, CTRL); av = ((av >= o) == (UP)) ? av : o; } while (0)
#define STEP_B_W(UP) do { u64 o; EX_W(o, av); av = ((av >= o) == (UP)) ? av : o; } while (0)

__global__ __launch_bounds__(BLK) void topk_route_kernel(
    const float* __restrict__ A, const int* __restrict__ topk,
    float* __restrict__ out_w, float* __restrict__ out_i, int NQ, int Q, int N) {
  __shared__ u64 cand[4][CAND];

  const unsigned tid = threadIdx.x;
  const unsigned wv = tid >> 6, lane = tid & 63u;
  const unsigned row = blockIdx.x * 4u + wv;
  if ((int)row >= NQ) return;
  const unsigned n = row / (unsigned)Q;

  // ---- load + mask fused (8x float4, coalesced within the wave)
  const float4* a4 = (const float4*)(A + (size_t)row * M_COLS);
  unsigned bits[32];
#pragma unroll
  for (int t = 0; t < 8; ++t) {
    float4 vv = a4[lane + 64u * (unsigned)t];
    bits[4 * t + 0] = __float_as_uint(vv.x) & 0x7fffffffu;
    bits[4 * t + 1] = __float_as_uint(vv.y) & 0x7fffffffu;
    bits[4 * t + 2] = __float_as_uint(vv.z) & 0x7fffffffu;
    bits[4 * t + 3] = __float_as_uint(vv.w) & 0x7fffffffu;
  }

  // zero pad slots of the upper half (lower 64 always overwritten: csel >= 64)
  cand[wv][lane + 64u] = 0ull;

  // ---- branch-free topk sniff (int64 vs int32 layout; uniform)
  int kk;
  if (N >= 8) {
    const int4* t4 = (const int4*)topk;
    int4 a = t4[0], b = t4[1], c = t4[2], d = t4[3];
    int k64 = topk[2 * (int)n], k32 = topk[(int)n];
    bool looks64 = (a.y == 0) & (a.w == 0) & (b.y == 0) & (b.w == 0) &
                   (c.y == 0) & (c.w == 0) & (d.y == 0) & (d.w == 0) &
                   (a.x >= 1) & (a.z >= 1) & (b.x >= 1) & (b.z >= 1) &
                   (c.x >= 1) & (c.z >= 1) & (d.x >= 1) & (d.z >= 1);
    kk = looks64 ? k64 : k32;
  } else {
    bool looks64 = true;
    for (int i = 0; i < N; ++i) {
      int l = topk[2 * i], h = topk[2 * i + 1];
      if (h != 0 || l < 1) { looks64 = false; break; }
    }
    kk = looks64 ? topk[2 * (int)n] : topk[(int)n];
  }
  kk = kk > M_COLS ? M_COLS : (kk < 0 ? 0 : kk);

  // ---- wave max -> uniform em
  unsigned mx = bits[0];
#pragma unroll
  for (int j = 1; j < 32; ++j) mx = bits[j] > mx ? bits[j] : mx;
  SCAN_MAX_U(mx);
  mx = RDL(mx, 63);
  const int em = (int)(mx >> 23);

  // attempt(T): keep-mask (4 independent 8-chains) + popc + DPP scan + total
  unsigned keep = 0u, sl = 0u, inc = 0u, csel = 0u;
  auto attempt = [&](unsigned T) {
    unsigned q0 = 0u, q1 = 0u, q2 = 0u, q3 = 0u;
#pragma unroll
    for (int j = 7; j >= 0; --j) {
      q0 = q0 + q0 + (unsigned)(bits[j] >= T);
      q1 = q1 + q1 + (unsigned)(bits[8 + j] >= T);
      q2 = q2 + q2 + (unsigned)(bits[16 + j] >= T);
      q3 = q3 + q3 + (unsigned)(bits[24 + j] >= T);
    }
    keep = q0 | (q1 << 8) | (q2 << 16) | (q3 << 24);
    sl = __popc(keep);
    inc = sl;
    SCAN_ADD_U(inc);
    csel = RDL(inc, 63);
  };

  // ---- probe em, em-1, em-2 (T=0 always qualifies: count=2048)
  unsigned lo, hi = mx + 1u;
  {
    unsigned T = (em > 0) ? ((unsigned)em << 23) : 0u;
    attempt(T); lo = T;
    if (csel < KOUT) {
      hi = T;
      T = (em - 1 > 0) ? ((unsigned)(em - 1) << 23) : 0u;
      attempt(T); lo = T;
      if (csel < KOUT) {
        hi = T;
        T = (em - 2 > 0) ? ((unsigned)(em - 2) << 23) : 0u;
        attempt(T); lo = T;
        if (csel < KOUT) { hi = T; attempt(0u); lo = 0u; }
      }
    }
  }

  // ---- rare: binary refine until 64 <= count(>=lo) <= 128
  {
    unsigned csel_lo = csel, lastT = lo;
    while (csel_lo > CAND && lo + 1u < hi) {
      unsigned mid = lo + ((hi - lo) >> 1);
      attempt(mid); lastT = mid;
      if (csel >= KOUT) { lo = mid; csel_lo = csel; } else hi = mid;
    }
    if (lastT != lo) attempt(lo);
  }

  // ---- ultra-rare: >128 ties at lo: keep all > lo + smallest-index ties
  if (csel > CAND) {
    unsigned kgt = 0u;
#pragma unroll
    for (int j = 31; j >= 0; --j) kgt = (kgt << 1) | (unsigned)(bits[j] >= hi);
    unsigned slgt = __popc(kgt), incgt = slgt;
    SCAN_ADD_U(incgt);
    unsigned cgt = RDL(incgt, 63);
    unsigned cap = CAND - cgt;
    keep = kgt;
    unsigned run = 0u;
#pragma unroll
    for (int t = 0; t < 8; ++t) {
      unsigned f = 0u;
#pragma unroll
      for (int c = 3; c >= 0; --c) f = (f << 1) | (unsigned)(bits[4 * t + c] == lo);
      unsigned tc = __popc(f), it = tc;
      SCAN_ADD_U(it);
      unsigned tbase = run + it - tc;
#pragma unroll
      for (int c = 0; c < 4; ++c) {
        if (f & (1u << c)) {
          if (tbase < cap) keep |= 1u << (4 * t + c);
          ++tbase;
        }
      }
      run += RDL(it, 63);
    }
    sl = __popc(keep);
    inc = sl;
    SCAN_ADD_U(inc);
    csel = RDL(inc, 63);
  }

  // ---- compaction: DPP-scanned base + popc-indexed independent stores
  unsigned base = inc - sl;  // exclusive prefix = write base
  const unsigned lobase = 2047u - 4u * lane;
  u64* cw = &cand[wv][0];
#pragma unroll
  for (int j = 0; j < 32; ++j) {
    if (keep & (1u << j)) {
      unsigned pj = base + (unsigned)__popc(keep & ((1u << j) - 1u));
      cw[pj] = ((u64)bits[j] << 32) |
               (u64)(lobase - (unsigned)((j >> 2) * 256 + (j & 3)));
    }
  }

  // ---- per-stage comparator flags from lane bits
  const bool b1 = (lane & 1u) != 0u, b2 = (lane & 2u) != 0u, b4 = (lane & 4u) != 0u;
  const bool b8 = (lane & 8u) != 0u, b16 = (lane & 16u) != 0u, b32 = (lane & 32u) != 0u;

  // ---- sort: k0 desc + k1 asc (21 dual stages), local exchange, merge top half
  u64 k0 = cw[lane];
  u64 k1 = cw[lane + 64u];
  // k=2
  STEP_A_D(0xB1, !(b2 ^ b1));
  // k=4
  STEP_A_D(0x4E, !(b4 ^ b2)); STEP_A_D(0xB1, !(b4 ^ b1));
  // k=8
  STEP_A_S(4, !(b8 ^ b4)); STEP_A_D(0x4E, !(b8 ^ b2)); STEP_A_D(0xB1, !(b8 ^ b1));
  // k=16
  STEP_A_S(8, !(b16 ^ b8)); STEP_A_S(4, !(b16 ^ b4));
  STEP_A_D(0x4E, !(b16 ^ b2)); STEP_A_D(0xB1, !(b16 ^ b1));
  // k=32
  STEP_A_S(16, !(b32 ^ b16)); STEP_A_S(8, !(b32 ^ b8)); STEP_A_S(4, !(b32 ^ b4));
  STEP_A_D(0x4E, !(b32 ^ b2)); STEP_A_D(0xB1, !(b32 ^ b1));
  // k=64 (lane&64 == 0 always)
  STEP_A_W(!b32);
  STEP_A_S(16, !b16); STEP_A_S(8, !b8); STEP_A_S(4, !b4);
  STEP_A_D(0x4E, !b2); STEP_A_D(0xB1, !b1);

  u64 av = k0 >= k1 ? k0 : k1;  // bitonic; holds the top-64 set
  STEP_B_W(!b32);
  STEP_B_S(16, !b16); STEP_B_S(8, !b8); STEP_B_S(4, !b4);
  STEP_B_D(0x4E, !b2); STEP_B_D(0xB1, !b1);

  // ---- softmax over first kk entries; lane = rank (sorted desc)
  float val = __uint_as_float((unsigned)(av >> 32));
  unsigned midx = 2047u - (unsigned)(av & 0xffffffffull);
  bool valid = (int)lane < kk;

  float vmx = __uint_as_float(
      (unsigned)__builtin_amdgcn_readfirstlane((int)(unsigned)(av >> 32)));
  float e = valid ? __expf(val - vmx) : 0.0f;
  float s = e;
  SCAN_ADD_F(s);
  float stot = __uint_as_float(RDL(__float_as_uint(s), 63));
  float w = valid ? (e / stot) : 0.0f;

  size_t o = (size_t)row * KOUT + lane;
  out_w[o] = w;
  out_i[o] = valid ? (float)midx : 0.0f;
}

extern "C" void kernel_launch(void* const* d_in, const int* in_sizes, int n_in,
                              void* d_out, int out_size, void* d_ws, size_t ws_size,
                              hipStream_t stream) {
  const float* A = (const float*)d_in[0];
  const int* topk = (const int*)d_in[1];
  float* out = (float*)d_out;
  const int NQ = in_sizes[0] / M_COLS;
  const int N = in_sizes[1] > 0 ? in_sizes[1] : 1;
  const int Q = NQ / N;
  float* out_w = out;
  float* out_i = out + (size_t)NQ * KOUT;
  const int blocks = (NQ + 3) / 4;
  hipLaunchKernelGGL(topk_route_kernel, dim3(blocks), dim3(BLK), 0, stream, A,
                     topk, out_w, out_i, NQ, Q, N);
}